// Round 13
// baseline (302.615 us; speedup 1.0000x reference)
//
#include <hip/hip_runtime.h>
#include <math.h>

#define NN 50000
#define EE 800000
#define DIN 128
#define F1 256          // HEADS*HID
#define NEG_SLOPE 0.2f

typedef _Float16 half8 __attribute__((ext_vector_type(8)));
typedef _Float16 h2 __attribute__((ext_vector_type(2)));
typedef float f32x4 __attribute__((ext_vector_type(4)));

#if __has_builtin(__builtin_amdgcn_fdot2)
#define FDOT2(a, b, c) __builtin_amdgcn_fdot2((a), (b), (c), false)
#else
#define FDOT2(a, b, c) ((float)(a)[0] * (float)(b)[0] + ((float)(a)[1] * (float)(b)[1] + (c)))
#endif

__device__ __forceinline__ ushort f2h(float f) {
    _Float16 h = (_Float16)f;
    return __builtin_bit_cast(ushort, h);
}

__device__ __forceinline__ void gload16(const void* g, void* l) {
    __builtin_amdgcn_global_load_lds(
        (const __attribute__((address_space(1))) void*)g,
        (__attribute__((address_space(3))) void*)l, 16, 0, 0);
}

// DPP-based xor-add reduce within aligned 8-lane groups (VALU pipe).
#if __has_builtin(__builtin_amdgcn_mov_dpp)
#define DPPADD(x, ctrl) ((x) + __int_as_float(__builtin_amdgcn_mov_dpp(__float_as_int(x), (ctrl), 0xF, 0xF, true)))
#define RED8(x) do { x = DPPADD(x, 0xB1); x = DPPADD(x, 0x4E); x = DPPADD(x, 0x141); } while (0)
#else
#define RED8(x) do { x += __shfl_xor(x, 1, 64); x += __shfl_xor(x, 2, 64); x += __shfl_xor(x, 4, 64); } while (0)
#endif

// ================= prep: count degrees + convert x and weights to fp16 =================
#define NX8 (NN * DIN / 8)      // 800000
#define W1SZ (512 * DIN)        // 65536
#define W2SZ (512 * 256)        // 131072
__global__ __launch_bounds__(256) void prep(
        const int* __restrict__ dst, int* __restrict__ deg,
        const float* __restrict__ x, ushort* __restrict__ xh,
        const float* __restrict__ Wl1, const float* __restrict__ Wr1,
        const float* __restrict__ Wl2, const float* __restrict__ Wr2,
        ushort* __restrict__ Wst1, ushort* __restrict__ Wst2) {
    int idx = blockIdx.x * 256 + threadIdx.x;
    if (idx < EE) {
        atomicAdd(&deg[dst[idx]], 1);
    } else if (idx < EE + NX8) {
        int i = idx - EE;
        float4 v0 = *(const float4*)(x + (size_t)i * 8);
        float4 v1 = *(const float4*)(x + (size_t)i * 8 + 4);
        ushort4 o0, o1;
        o0.x = f2h(v0.x); o0.y = f2h(v0.y); o0.z = f2h(v0.z); o0.w = f2h(v0.w);
        o1.x = f2h(v1.x); o1.y = f2h(v1.y); o1.z = f2h(v1.z); o1.w = f2h(v1.w);
        *(ushort4*)(xh + (size_t)i * 8) = o0;
        *(ushort4*)(xh + (size_t)i * 8 + 4) = o1;
    } else {
        int j = idx - EE - NX8;
        if (j < W1SZ) {
            int n = j >> 7, k = j & 127;        // Wst1[n][k], K=128
            float v = (n < 256) ? Wl1[(size_t)k * 256 + n] : Wr1[(size_t)k * 256 + (n - 256)];
            Wst1[j] = f2h(v);
        } else if (j < W1SZ + W2SZ) {
            int jj = j - W1SZ;
            int n = jj >> 8, k = jj & 255;      // Wst2[n][k], K=256
            float v = (n < 256) ? Wl2[(size_t)k * 256 + n] : Wr2[(size_t)k * 256 + (n - 256)];
            Wst2[jj] = f2h(v);
        }
    }
}

// ================= fused fp16 MFMA GEMM: C[M,512] = A[M,K] @ [Wl;Wr]^T + bias =================
__global__ __launch_bounds__(256) void gemm_mfma2(
        const ushort* __restrict__ Ah, const ushort* __restrict__ Wst,
        const float* __restrict__ biasL, const float* __restrict__ biasR,
        ushort* __restrict__ Ch, int M, int K) {
    __shared__ ushort As[128 * 32];   // [row][slot*8]  (slot-rotated)
    __shared__ ushort Ws[128 * 32];   // [col][slot*8]
    const int tid = threadIdx.x;
    const int wave = tid >> 6, lane = tid & 63;
    const int row0 = blockIdx.x * 128;
    const int col0 = blockIdx.y * 128;          // 0..3 -> 512 cols
    const int wr = wave >> 1, wc = wave & 1;
    const int g = lane >> 4, lr = lane & 15;

    f32x4 acc[4][4];
    #pragma unroll
    for (int m = 0; m < 4; m++)
        #pragma unroll
        for (int n = 0; n < 4; n++) acc[m][n] = (f32x4){0.f, 0.f, 0.f, 0.f};

    for (int k0 = 0; k0 < K; k0 += 32) {
        #pragma unroll
        for (int j = 0; j < 2; j++) {
            int cc = j * 256 + wave * 64 + lane;       // 0..511, 8 ushorts each
            int rr = cc >> 2;
            int kp = ((cc & 3) - (rr >> 1)) & 3;       // slot rotation (stage side)
            int gr = row0 + rr; if (gr >= M) gr = M - 1;
            gload16(Ah + (size_t)gr * K + k0 + kp * 8, &As[(j * 256 + wave * 64) * 8]);
            gload16(Wst + (size_t)(col0 + rr) * K + k0 + kp * 8, &Ws[(j * 256 + wave * 64) * 8]);
        }
        __syncthreads();
        half8 af[4], bfr[4];
        #pragma unroll
        for (int m = 0; m < 4; m++) {
            int row = wr * 64 + m * 16 + lr;
            int slot = (g + (row >> 1)) & 3;           // rotation (read side)
            af[m] = *(const half8*)&As[(row * 4 + slot) * 8];
        }
        #pragma unroll
        for (int n = 0; n < 4; n++) {
            int col = wc * 64 + n * 16 + lr;
            int slot = (g + (col >> 1)) & 3;
            bfr[n] = *(const half8*)&Ws[(col * 4 + slot) * 8];
        }
        #pragma unroll
        for (int m = 0; m < 4; m++)
            #pragma unroll
            for (int n = 0; n < 4; n++)
                acc[m][n] = __builtin_amdgcn_mfma_f32_16x16x32_f16(af[m], bfr[n], acc[m][n], 0, 0, 0);
        __syncthreads();
    }
    #pragma unroll
    for (int m = 0; m < 4; m++) {
        int rowb = row0 + wr * 64 + m * 16 + g * 4;
        #pragma unroll
        for (int n = 0; n < 4; n++) {
            int col = col0 + wc * 64 + n * 16 + lr;
            float b = (col < 256) ? biasL[col] : biasR[col - 256];
            #pragma unroll
            for (int j = 0; j < 4; j++) {
                int grow = rowb + j;
                if (grow < M) Ch[(size_t)grow * 512 + col] = f2h(acc[m][n][j] + b);
            }
        }
    }
}

// ================= CSR scan kernels =================
__global__ __launch_bounds__(256) void scanA(
        const int* __restrict__ deg, int* __restrict__ inc, int* __restrict__ bsum) {
    __shared__ int s[256];
    int i = blockIdx.x * 256 + threadIdx.x;
    int v = (i < NN) ? deg[i] : 0;
    s[threadIdx.x] = v;
    __syncthreads();
    #pragma unroll
    for (int off = 1; off < 256; off <<= 1) {
        int t = (threadIdx.x >= off) ? s[threadIdx.x - off] : 0;
        __syncthreads();
        s[threadIdx.x] += t;
        __syncthreads();
    }
    if (i < NN) inc[i] = s[threadIdx.x];
    if (threadIdx.x == 255) bsum[blockIdx.x] = s[255];
}

__global__ __launch_bounds__(256) void scanB(
        const int* __restrict__ bsum, int* __restrict__ boff, int nblocks) {
    __shared__ int s[256];
    int v = (threadIdx.x < nblocks) ? bsum[threadIdx.x] : 0;
    s[threadIdx.x] = v;
    __syncthreads();
    #pragma unroll
    for (int off = 1; off < 256; off <<= 1) {
        int t = (threadIdx.x >= off) ? s[threadIdx.x - off] : 0;
        __syncthreads();
        s[threadIdx.x] += t;
        __syncthreads();
    }
    if (threadIdx.x < nblocks) boff[threadIdx.x] = s[threadIdx.x] - v;
}

__global__ __launch_bounds__(256) void scanC(
        const int* __restrict__ deg, const int* __restrict__ inc,
        const int* __restrict__ boff,
        int* __restrict__ rowptr, int* __restrict__ wptr) {
    int i = blockIdx.x * 256 + threadIdx.x;
    if (i < NN) {
        int ex = inc[i] - deg[i] + boff[i >> 8];
        rowptr[i] = ex;
        wptr[i] = ex;
    } else if (i == NN) {
        rowptr[NN] = EE;
    }
}

__global__ __launch_bounds__(256) void scatter_src(
        const int* __restrict__ src, const int* __restrict__ dst,
        int* __restrict__ wptr, int* __restrict__ ssrc) {
    int e = blockIdx.x * 256 + threadIdx.x;
    if (e < EE) {
        int pos = atomicAdd(&wptr[dst[e]], 1);
        ssrc[pos] = src[e];
    }
}

// ================= fused GATv2 node kernel (fp16 packed, 2-edge ILP, DPP reduce) =================
// hb: [N][512] fp16, cols 0-255 = xl, cols 256-511 = xr.
// One wave per node, two 32-lane halves; each half processes its edge subset
// TWO edges per iteration. Lane owns 8 channels (head = (lane&31)>>3).
// Plain-exp softmax (logits bounded). Head reduce fully in DPP.
template<int MODE>
__global__ __launch_bounds__(256) void gat_node(
        const ushort* __restrict__ hb,
        const float* __restrict__ att,
        const int* __restrict__ rowptr, const int* __restrict__ ssrc,
        const float* __restrict__ bias,
        const float* __restrict__ Wout, const float* __restrict__ bout,
        ushort* __restrict__ out_h, float* __restrict__ out_f) {
    int node = blockIdx.x * 4 + (threadIdx.x >> 6);
    int lane = threadIdx.x & 63;
    if (node >= NN) return;
    const int half = lane >> 5;
    const int hl = lane & 31;

    const int beg = rowptr[node];
    const int cnt = rowptr[node + 1] - beg;
    const int cntA = (cnt + 1) >> 1;
    const int mybeg = beg + half * cntA;
    const int mycnt = half ? (cnt - cntA) : cntA;

    const h2 nsh = { (_Float16)NEG_SLOPE, (_Float16)NEG_SLOPE };

    // xr (fp16 packed) and att (converted to fp16 pairs)
    h2 rrh[4], ath[4];
    {
        uint4 ur = *(const uint4*)(hb + (size_t)node * 512 + 256 + hl * 8);
        rrh[0] = __builtin_bit_cast(h2, ur.x);
        rrh[1] = __builtin_bit_cast(h2, ur.y);
        rrh[2] = __builtin_bit_cast(h2, ur.z);
        rrh[3] = __builtin_bit_cast(h2, ur.w);
        const float* pat = att + hl * 8;
        #pragma unroll
        for (int k2 = 0; k2 < 4; k2++) {
            h2 t; t[0] = (_Float16)pat[k2 * 2]; t[1] = (_Float16)pat[k2 * 2 + 1];
            ath[k2] = t;
        }
    }

    float den = 0.f;
    float acc[8] = {0.f, 0.f, 0.f, 0.f, 0.f, 0.f, 0.f, 0.f};

    for (int it = 0; it < cntA; it += 2) {
        const bool v0 = (it < mycnt);
        const bool v1 = (it + 1 < mycnt);
        // invalid slots clamp to beg (valid whenever the loop runs: cntA>0 -> cnt>0)
        int i0 = v0 ? mybeg + it : beg;
        int i1 = v1 ? mybeg + it + 1 : beg;
        int s0 = ssrc[i0];
        int s1 = ssrc[i1];

        uint4 ud0 = *(const uint4*)(hb + (size_t)s0 * 512 + hl * 8);
        uint4 ud1 = *(const uint4*)(hb + (size_t)s1 * 512 + hl * 8);
        h2 xa[4], xb[4];
        xa[0] = __builtin_bit_cast(h2, ud0.x); xb[0] = __builtin_bit_cast(h2, ud1.x);
        xa[1] = __builtin_bit_cast(h2, ud0.y); xb[1] = __builtin_bit_cast(h2, ud1.y);
        xa[2] = __builtin_bit_cast(h2, ud0.z); xb[2] = __builtin_bit_cast(h2, ud1.z);
        xa[3] = __builtin_bit_cast(h2, ud0.w); xb[3] = __builtin_bit_cast(h2, ud1.w);

        float pa = 0.f, pb = 0.f;
        #pragma unroll
        for (int k2 = 0; k2 < 4; k2++) {
            h2 va = xa[k2] + rrh[k2];
            h2 vb = xb[k2] + rrh[k2];
            h2 la = __builtin_elementwise_max(va, va * nsh);
            h2 lb = __builtin_elementwise_max(vb, vb * nsh);
            pa = FDOT2(la, ath[k2], pa);
            pb = FDOT2(lb, ath[k2], pb);
        }
        RED8(pa);
        RED8(pb);

        float p0 = v0 ? __expf(pa) : 0.f;
        float p1 = v1 ? __expf(pb) : 0.f;
        den += p0 + p1;
        #pragma unroll
        for (int k2 = 0; k2 < 4; k2++) {
            acc[k2 * 2 + 0] = fmaf(p0, (float)xa[k2][0], acc[k2 * 2 + 0]);
            acc[k2 * 2 + 1] = fmaf(p0, (float)xa[k2][1], acc[k2 * 2 + 1]);
            acc[k2 * 2 + 0] = fmaf(p1, (float)xb[k2][0], acc[k2 * 2 + 0]);
            acc[k2 * 2 + 1] = fmaf(p1, (float)xb[k2][1], acc[k2 * 2 + 1]);
        }
    }

    // merge the two half-wave streams
    den += __shfl_xor(den, 32, 64);
    float inv = den > 0.f ? 1.0f / den : 0.f;
    float o[8];
    #pragma unroll
    for (int c = 0; c < 8; c++) {
        float t = acc[c] + __shfl_xor(acc[c], 32, 64);
        o[c] = t * inv;
    }

    if (MODE == 1) {
        // bias + relu -> fp16, packed [N][256]; half 0 writes 16B
        uint4 ow;
        float t0, t1;
        t0 = o[0] + bias[hl * 8 + 0]; t0 = t0 > 0.f ? t0 : 0.f;
        t1 = o[1] + bias[hl * 8 + 1]; t1 = t1 > 0.f ? t1 : 0.f;
        ow.x = (unsigned)f2h(t0) | ((unsigned)f2h(t1) << 16);
        t0 = o[2] + bias[hl * 8 + 2]; t0 = t0 > 0.f ? t0 : 0.f;
        t1 = o[3] + bias[hl * 8 + 3]; t1 = t1 > 0.f ? t1 : 0.f;
        ow.y = (unsigned)f2h(t0) | ((unsigned)f2h(t1) << 16);
        t0 = o[4] + bias[hl * 8 + 4]; t0 = t0 > 0.f ? t0 : 0.f;
        t1 = o[5] + bias[hl * 8 + 5]; t1 = t1 > 0.f ? t1 : 0.f;
        ow.z = (unsigned)f2h(t0) | ((unsigned)f2h(t1) << 16);
        t0 = o[6] + bias[hl * 8 + 6]; t0 = t0 > 0.f ? t0 : 0.f;
        t1 = o[7] + bias[hl * 8 + 7]; t1 = t1 > 0.f ? t1 : 0.f;
        ow.w = (unsigned)f2h(t0) | ((unsigned)f2h(t1) << 16);
        if (half == 0)
            *(uint4*)(out_h + (size_t)node * 256 + hl * 8) = ow;
    } else {
        // head-mean (lanes hl^8, hl^16) + bias2, then @ Wout + bout
        #pragma unroll
        for (int c = 0; c < 8; c++) {
            o[c] += __shfl_xor(o[c], 8, 64);
            o[c] += __shfl_xor(o[c], 16, 64);
        }
        int c64 = (hl & 7) * 8;
        float o0 = 0.f, o1 = 0.f;
        #pragma unroll
        for (int c = 0; c < 8; c++) {
            float t = 0.25f * o[c] + bias[c64 + c];
            o0 = fmaf(t, Wout[(c64 + c) * 2 + 0], o0);
            o1 = fmaf(t, Wout[(c64 + c) * 2 + 1], o1);
        }
        o0 += __shfl_xor(o0, 1, 64); o1 += __shfl_xor(o1, 1, 64);
        o0 += __shfl_xor(o0, 2, 64); o1 += __shfl_xor(o1, 2, 64);
        o0 += __shfl_xor(o0, 4, 64); o1 += __shfl_xor(o1, 4, 64);
        if (lane == 0) {
            out_f[(size_t)node * 2 + 0] = o0 + bout[0];
            out_f[(size_t)node * 2 + 1] = o1 + bout[1];
        }
    }
}

extern "C" void kernel_launch(void* const* d_in, const int* in_sizes, int n_in,
                              void* d_out, int out_size, void* d_ws, size_t ws_size,
                              hipStream_t stream) {
    const float* x     = (const float*)d_in[0];
    const int*   ei    = (const int*)d_in[1];
    const float* Wl1   = (const float*)d_in[2];
    const float* bl1   = (const float*)d_in[3];
    const float* Wr1   = (const float*)d_in[4];
    const float* br1   = (const float*)d_in[5];
    const float* att1  = (const float*)d_in[6];
    const float* bias1 = (const float*)d_in[7];
    const float* Wl2   = (const float*)d_in[8];
    const float* bl2   = (const float*)d_in[9];
    const float* Wr2   = (const float*)d_in[10];
    const float* br2   = (const float*)d_in[11];
    const float* att2  = (const float*)d_in[12];
    const float* bias2 = (const float*)d_in[13];
    const float* Wout  = (const float*)d_in[14];
    const float* bout  = (const float*)d_in[15];

    const int* src = ei;
    const int* dst = ei + EE;

    // ---------- workspace layout ----------
    ushort* hb    = (ushort*)d_ws;                     // [N][512] fp16 (xl|xr)
    ushort* h1_h  = hb + (size_t)NN * 512;             // [N][256] fp16
    ushort* xh    = h1_h + (size_t)NN * 256;           // [N][128] fp16
    ushort* Wst1  = xh + (size_t)NN * DIN;             // [512][128]
    ushort* Wst2  = Wst1 + W1SZ;                       // [512][256]
    int* deg    = (int*)(Wst2 + W2SZ);
    int* inc    = deg + NN;
    int* rowptr = inc + NN;                            // NN+1
    int* wptr   = rowptr + NN + 1;
    int* ssrc   = wptr + NN;                           // E
    int* bsum   = ssrc + EE;                           // 256
    int* boff   = bsum + 256;

    const int scanBlocks = (NN + 255) / 256;
    const int edgeBlocks = (EE + 255) / 256;
    const int nodeBlocks = (NN + 3) / 4;
    const int prepBlocks = (EE + NX8 + W1SZ + W2SZ + 255) / 256;
    dim3 gemmGrid((NN + 127) / 128, 4);

    // ---------- CSR build + converts ----------
    hipMemsetAsync(deg, 0, NN * sizeof(int), stream);
    prep<<<prepBlocks, 256, 0, stream>>>(dst, deg, x, xh, Wl1, Wr1, Wl2, Wr2, Wst1, Wst2);
    scanA<<<scanBlocks, 256, 0, stream>>>(deg, inc, bsum);
    scanB<<<1, 256, 0, stream>>>(bsum, boff, scanBlocks);
    scanC<<<scanBlocks + 1, 256, 0, stream>>>(deg, inc, boff, rowptr, wptr);
    scatter_src<<<edgeBlocks, 256, 0, stream>>>(src, dst, wptr, ssrc);

    // ---------- layer 1 ----------
    gemm_mfma2<<<gemmGrid, 256, 0, stream>>>(xh, Wst1, bl1, br1, hb, NN, DIN);
    gat_node<1><<<nodeBlocks, 256, 0, stream>>>(hb, att1, rowptr, ssrc,
                                                bias1, nullptr, nullptr, h1_h, nullptr);

    // ---------- layer 2 ----------
    gemm_mfma2<<<gemmGrid, 256, 0, stream>>>(h1_h, Wst2, bl2, br2, hb, NN, 256);
    gat_node<2><<<nodeBlocks, 256, 0, stream>>>(hb, att2, rowptr, ssrc,
                                                bias2, Wout, bout, nullptr, (float*)d_out);
}

// Round 14
// 297.505 us; speedup vs baseline: 1.0172x; 1.0172x over previous
//
#include <hip/hip_runtime.h>
#include <math.h>

#define NN 50000
#define EE 800000
#define DIN 128
#define F1 256          // HEADS*HID
#define NEG_SLOPE 0.2f

typedef _Float16 half8 __attribute__((ext_vector_type(8)));
typedef _Float16 h2 __attribute__((ext_vector_type(2)));
typedef float f32x4 __attribute__((ext_vector_type(4)));

#if __has_builtin(__builtin_amdgcn_fdot2)
#define FDOT2(a, b, c) __builtin_amdgcn_fdot2((a), (b), (c), false)
#else
#define FDOT2(a, b, c) ((float)(a)[0] * (float)(b)[0] + ((float)(a)[1] * (float)(b)[1] + (c)))
#endif

__device__ __forceinline__ ushort f2h(float f) {
    _Float16 h = (_Float16)f;
    return __builtin_bit_cast(ushort, h);
}

__device__ __forceinline__ void gload16(const void* g, void* l) {
    __builtin_amdgcn_global_load_lds(
        (const __attribute__((address_space(1))) void*)g,
        (__attribute__((address_space(3))) void*)l, 16, 0, 0);
}

// DPP-based xor-add reduce within aligned 8-lane groups (VALU pipe).
#if __has_builtin(__builtin_amdgcn_mov_dpp)
#define DPPADD(x, ctrl) ((x) + __int_as_float(__builtin_amdgcn_mov_dpp(__float_as_int(x), (ctrl), 0xF, 0xF, true)))
#define RED8(x) do { x = DPPADD(x, 0xB1); x = DPPADD(x, 0x4E); x = DPPADD(x, 0x141); } while (0)
#else
#define RED8(x) do { x += __shfl_xor(x, 1, 64); x += __shfl_xor(x, 2, 64); x += __shfl_xor(x, 4, 64); } while (0)
#endif

// ================= prep: count degrees + convert x and weights to fp16 =================
#define NX8 (NN * DIN / 8)      // 800000
#define W1SZ (512 * DIN)        // 65536
#define W2SZ (512 * 256)        // 131072
__global__ __launch_bounds__(256) void prep(
        const int* __restrict__ dst, int* __restrict__ deg,
        const float* __restrict__ x, ushort* __restrict__ xh,
        const float* __restrict__ Wl1, const float* __restrict__ Wr1,
        const float* __restrict__ Wl2, const float* __restrict__ Wr2,
        ushort* __restrict__ Wst1, ushort* __restrict__ Wst2) {
    int idx = blockIdx.x * 256 + threadIdx.x;
    if (idx < EE) {
        atomicAdd(&deg[dst[idx]], 1);
    } else if (idx < EE + NX8) {
        int i = idx - EE;
        float4 v0 = *(const float4*)(x + (size_t)i * 8);
        float4 v1 = *(const float4*)(x + (size_t)i * 8 + 4);
        ushort4 o0, o1;
        o0.x = f2h(v0.x); o0.y = f2h(v0.y); o0.z = f2h(v0.z); o0.w = f2h(v0.w);
        o1.x = f2h(v1.x); o1.y = f2h(v1.y); o1.z = f2h(v1.z); o1.w = f2h(v1.w);
        *(ushort4*)(xh + (size_t)i * 8) = o0;
        *(ushort4*)(xh + (size_t)i * 8 + 4) = o1;
    } else {
        int j = idx - EE - NX8;
        if (j < W1SZ) {
            int n = j >> 7, k = j & 127;        // Wst1[n][k], K=128
            float v = (n < 256) ? Wl1[(size_t)k * 256 + n] : Wr1[(size_t)k * 256 + (n - 256)];
            Wst1[j] = f2h(v);
        } else if (j < W1SZ + W2SZ) {
            int jj = j - W1SZ;
            int n = jj >> 8, k = jj & 255;      // Wst2[n][k], K=256
            float v = (n < 256) ? Wl2[(size_t)k * 256 + n] : Wr2[(size_t)k * 256 + (n - 256)];
            Wst2[jj] = f2h(v);
        }
    }
}

// ================= fused fp16 MFMA GEMM: C[M,512] = A[M,K] @ [Wl;Wr]^T + bias =================
__global__ __launch_bounds__(256) void gemm_mfma2(
        const ushort* __restrict__ Ah, const ushort* __restrict__ Wst,
        const float* __restrict__ biasL, const float* __restrict__ biasR,
        ushort* __restrict__ Ch, int M, int K) {
    __shared__ ushort As[128 * 32];   // [row][slot*8]  (slot-rotated)
    __shared__ ushort Ws[128 * 32];   // [col][slot*8]
    const int tid = threadIdx.x;
    const int wave = tid >> 6, lane = tid & 63;
    const int row0 = blockIdx.x * 128;
    const int col0 = blockIdx.y * 128;          // 0..3 -> 512 cols
    const int wr = wave >> 1, wc = wave & 1;
    const int g = lane >> 4, lr = lane & 15;

    f32x4 acc[4][4];
    #pragma unroll
    for (int m = 0; m < 4; m++)
        #pragma unroll
        for (int n = 0; n < 4; n++) acc[m][n] = (f32x4){0.f, 0.f, 0.f, 0.f};

    for (int k0 = 0; k0 < K; k0 += 32) {
        #pragma unroll
        for (int j = 0; j < 2; j++) {
            int cc = j * 256 + wave * 64 + lane;       // 0..511, 8 ushorts each
            int rr = cc >> 2;
            int kp = ((cc & 3) - (rr >> 1)) & 3;       // slot rotation (stage side)
            int gr = row0 + rr; if (gr >= M) gr = M - 1;
            gload16(Ah + (size_t)gr * K + k0 + kp * 8, &As[(j * 256 + wave * 64) * 8]);
            gload16(Wst + (size_t)(col0 + rr) * K + k0 + kp * 8, &Ws[(j * 256 + wave * 64) * 8]);
        }
        __syncthreads();
        half8 af[4], bfr[4];
        #pragma unroll
        for (int m = 0; m < 4; m++) {
            int row = wr * 64 + m * 16 + lr;
            int slot = (g + (row >> 1)) & 3;           // rotation (read side)
            af[m] = *(const half8*)&As[(row * 4 + slot) * 8];
        }
        #pragma unroll
        for (int n = 0; n < 4; n++) {
            int col = wc * 64 + n * 16 + lr;
            int slot = (g + (col >> 1)) & 3;
            bfr[n] = *(const half8*)&Ws[(col * 4 + slot) * 8];
        }
        #pragma unroll
        for (int m = 0; m < 4; m++)
            #pragma unroll
            for (int n = 0; n < 4; n++)
                acc[m][n] = __builtin_amdgcn_mfma_f32_16x16x32_f16(af[m], bfr[n], acc[m][n], 0, 0, 0);
        __syncthreads();
    }
    #pragma unroll
    for (int m = 0; m < 4; m++) {
        int rowb = row0 + wr * 64 + m * 16 + g * 4;
        #pragma unroll
        for (int n = 0; n < 4; n++) {
            int col = col0 + wc * 64 + n * 16 + lr;
            float b = (col < 256) ? biasL[col] : biasR[col - 256];
            #pragma unroll
            for (int j = 0; j < 4; j++) {
                int grow = rowb + j;
                if (grow < M) Ch[(size_t)grow * 512 + col] = f2h(acc[m][n][j] + b);
            }
        }
    }
}

// ================= CSR scan kernels =================
__global__ __launch_bounds__(256) void scanA(
        const int* __restrict__ deg, int* __restrict__ inc, int* __restrict__ bsum) {
    __shared__ int s[256];
    int i = blockIdx.x * 256 + threadIdx.x;
    int v = (i < NN) ? deg[i] : 0;
    s[threadIdx.x] = v;
    __syncthreads();
    #pragma unroll
    for (int off = 1; off < 256; off <<= 1) {
        int t = (threadIdx.x >= off) ? s[threadIdx.x - off] : 0;
        __syncthreads();
        s[threadIdx.x] += t;
        __syncthreads();
    }
    if (i < NN) inc[i] = s[threadIdx.x];
    if (threadIdx.x == 255) bsum[blockIdx.x] = s[255];
}

__global__ __launch_bounds__(256) void scanB(
        const int* __restrict__ bsum, int* __restrict__ boff, int nblocks) {
    __shared__ int s[256];
    int v = (threadIdx.x < nblocks) ? bsum[threadIdx.x] : 0;
    s[threadIdx.x] = v;
    __syncthreads();
    #pragma unroll
    for (int off = 1; off < 256; off <<= 1) {
        int t = (threadIdx.x >= off) ? s[threadIdx.x - off] : 0;
        __syncthreads();
        s[threadIdx.x] += t;
        __syncthreads();
    }
    if (threadIdx.x < nblocks) boff[threadIdx.x] = s[threadIdx.x] - v;
}

__global__ __launch_bounds__(256) void scanC(
        const int* __restrict__ deg, const int* __restrict__ inc,
        const int* __restrict__ boff,
        int* __restrict__ rowptr, int* __restrict__ wptr) {
    int i = blockIdx.x * 256 + threadIdx.x;
    if (i < NN) {
        int ex = inc[i] - deg[i] + boff[i >> 8];
        rowptr[i] = ex;
        wptr[i] = ex;
    } else if (i == NN) {
        rowptr[NN] = EE;
    }
}

__global__ __launch_bounds__(256) void scatter_src(
        const int* __restrict__ src, const int* __restrict__ dst,
        int* __restrict__ wptr, int* __restrict__ ssrc) {
    int e = blockIdx.x * 256 + threadIdx.x;
    if (e < EE) {
        int pos = atomicAdd(&wptr[dst[e]], 1);
        ssrc[pos] = src[e];
    }
}

// ================= fused GATv2 node kernel =================
// fp16 packed, 2-edge per iteration, depth-2 software pipeline:
// iteration `it` computes on rows prefetched during `it-2`, while issuing
// the gathers for `it+2`. hb: [N][512] fp16 (xl | xr).
// Lane owns 8 channels (head = (lane&31)>>3). Plain-exp softmax.
template<int MODE>
__global__ __launch_bounds__(256) void gat_node(
        const ushort* __restrict__ hb,
        const float* __restrict__ att,
        const int* __restrict__ rowptr, const int* __restrict__ ssrc,
        const float* __restrict__ bias,
        const float* __restrict__ Wout, const float* __restrict__ bout,
        ushort* __restrict__ out_h, float* __restrict__ out_f) {
    int node = blockIdx.x * 4 + (threadIdx.x >> 6);
    int lane = threadIdx.x & 63;
    if (node >= NN) return;
    const int half = lane >> 5;
    const int hl = lane & 31;

    const int beg = rowptr[node];
    const int cnt = rowptr[node + 1] - beg;
    const int cntA = (cnt + 1) >> 1;
    const int mybeg = beg + half * cntA;
    const int mycnt = half ? (cnt - cntA) : cntA;

    const h2 nsh = { (_Float16)NEG_SLOPE, (_Float16)NEG_SLOPE };

    // xr (fp16 packed) and att (converted to fp16 pairs)
    h2 rrh[4], ath[4];
    {
        uint4 ur = *(const uint4*)(hb + (size_t)node * 512 + 256 + hl * 8);
        rrh[0] = __builtin_bit_cast(h2, ur.x);
        rrh[1] = __builtin_bit_cast(h2, ur.y);
        rrh[2] = __builtin_bit_cast(h2, ur.z);
        rrh[3] = __builtin_bit_cast(h2, ur.w);
        const float* pat = att + hl * 8;
        #pragma unroll
        for (int k2 = 0; k2 < 4; k2++) {
            h2 t; t[0] = (_Float16)pat[k2 * 2]; t[1] = (_Float16)pat[k2 * 2 + 1];
            ath[k2] = t;
        }
    }

    float den = 0.f;
    float acc[8] = {0.f, 0.f, 0.f, 0.f, 0.f, 0.f, 0.f, 0.f};

    // ---- pipeline prologue: fetch rows for it=0 ----
    // safe fallback index 0 when this node/half has no edges (ssrc[0] valid, result unused)
    int p0 = (0 < mycnt) ? mybeg + 0 : ((cnt > 0) ? beg : 0);
    int p1 = (1 < mycnt) ? mybeg + 1 : ((cnt > 0) ? beg : 0);
    int s0 = ssrc[p0];
    int s1 = ssrc[p1];
    uint4 cur0 = *(const uint4*)(hb + (size_t)s0 * 512 + hl * 8);
    uint4 cur1 = *(const uint4*)(hb + (size_t)s1 * 512 + hl * 8);

    for (int it = 0; it < cntA; it += 2) {
        const bool v0 = (it < mycnt);
        const bool v1 = (it + 1 < mycnt);

        // ---- issue next-next stage (it+2) index + row loads (independent of math) ----
        int n0 = (it + 2 < mycnt) ? mybeg + it + 2 : beg;   // beg valid: loop runs => cnt>0
        int n1 = (it + 3 < mycnt) ? mybeg + it + 3 : beg;
        int ns0 = ssrc[n0];
        int ns1 = ssrc[n1];
        uint4 nxt0 = *(const uint4*)(hb + (size_t)ns0 * 512 + hl * 8);
        uint4 nxt1 = *(const uint4*)(hb + (size_t)ns1 * 512 + hl * 8);

        // ---- math on current stage ----
        h2 xa[4], xb[4];
        xa[0] = __builtin_bit_cast(h2, cur0.x); xb[0] = __builtin_bit_cast(h2, cur1.x);
        xa[1] = __builtin_bit_cast(h2, cur0.y); xb[1] = __builtin_bit_cast(h2, cur1.y);
        xa[2] = __builtin_bit_cast(h2, cur0.z); xb[2] = __builtin_bit_cast(h2, cur1.z);
        xa[3] = __builtin_bit_cast(h2, cur0.w); xb[3] = __builtin_bit_cast(h2, cur1.w);

        float pa = 0.f, pb = 0.f;
        #pragma unroll
        for (int k2 = 0; k2 < 4; k2++) {
            h2 va = xa[k2] + rrh[k2];
            h2 vb = xb[k2] + rrh[k2];
            h2 la = __builtin_elementwise_max(va, va * nsh);
            h2 lb = __builtin_elementwise_max(vb, vb * nsh);
            pa = FDOT2(la, ath[k2], pa);
            pb = FDOT2(lb, ath[k2], pb);
        }
        RED8(pa);
        RED8(pb);

        float p0f = v0 ? __expf(pa) : 0.f;
        float p1f = v1 ? __expf(pb) : 0.f;
        den += p0f + p1f;
        #pragma unroll
        for (int k2 = 0; k2 < 4; k2++) {
            acc[k2 * 2 + 0] = fmaf(p0f, (float)xa[k2][0], acc[k2 * 2 + 0]);
            acc[k2 * 2 + 1] = fmaf(p0f, (float)xa[k2][1], acc[k2 * 2 + 1]);
            acc[k2 * 2 + 0] = fmaf(p1f, (float)xb[k2][0], acc[k2 * 2 + 0]);
            acc[k2 * 2 + 1] = fmaf(p1f, (float)xb[k2][1], acc[k2 * 2 + 1]);
        }

        // ---- rotate pipeline ----
        cur0 = nxt0;
        cur1 = nxt1;
    }

    // merge the two half-wave streams
    den += __shfl_xor(den, 32, 64);
    float inv = den > 0.f ? 1.0f / den : 0.f;
    float o[8];
    #pragma unroll
    for (int c = 0; c < 8; c++) {
        float t = acc[c] + __shfl_xor(acc[c], 32, 64);
        o[c] = t * inv;
    }

    if (MODE == 1) {
        // bias + relu -> fp16, packed [N][256]; half 0 writes 16B
        uint4 ow;
        float t0, t1;
        t0 = o[0] + bias[hl * 8 + 0]; t0 = t0 > 0.f ? t0 : 0.f;
        t1 = o[1] + bias[hl * 8 + 1]; t1 = t1 > 0.f ? t1 : 0.f;
        ow.x = (unsigned)f2h(t0) | ((unsigned)f2h(t1) << 16);
        t0 = o[2] + bias[hl * 8 + 2]; t0 = t0 > 0.f ? t0 : 0.f;
        t1 = o[3] + bias[hl * 8 + 3]; t1 = t1 > 0.f ? t1 : 0.f;
        ow.y = (unsigned)f2h(t0) | ((unsigned)f2h(t1) << 16);
        t0 = o[4] + bias[hl * 8 + 4]; t0 = t0 > 0.f ? t0 : 0.f;
        t1 = o[5] + bias[hl * 8 + 5]; t1 = t1 > 0.f ? t1 : 0.f;
        ow.z = (unsigned)f2h(t0) | ((unsigned)f2h(t1) << 16);
        t0 = o[6] + bias[hl * 8 + 6]; t0 = t0 > 0.f ? t0 : 0.f;
        t1 = o[7] + bias[hl * 8 + 7]; t1 = t1 > 0.f ? t1 : 0.f;
        ow.w = (unsigned)f2h(t0) | ((unsigned)f2h(t1) << 16);
        if (half == 0)
            *(uint4*)(out_h + (size_t)node * 256 + hl * 8) = ow;
    } else {
        // head-mean (lanes hl^8, hl^16) + bias2, then @ Wout + bout
        #pragma unroll
        for (int c = 0; c < 8; c++) {
            o[c] += __shfl_xor(o[c], 8, 64);
            o[c] += __shfl_xor(o[c], 16, 64);
        }
        int c64 = (hl & 7) * 8;
        float o0 = 0.f, o1 = 0.f;
        #pragma unroll
        for (int c = 0; c < 8; c++) {
            float t = 0.25f * o[c] + bias[c64 + c];
            o0 = fmaf(t, Wout[(c64 + c) * 2 + 0], o0);
            o1 = fmaf(t, Wout[(c64 + c) * 2 + 1], o1);
        }
        o0 += __shfl_xor(o0, 1, 64); o1 += __shfl_xor(o1, 1, 64);
        o0 += __shfl_xor(o0, 2, 64); o1 += __shfl_xor(o1, 2, 64);
        o0 += __shfl_xor(o0, 4, 64); o1 += __shfl_xor(o1, 4, 64);
        if (lane == 0) {
            out_f[(size_t)node * 2 + 0] = o0 + bout[0];
            out_f[(size_t)node * 2 + 1] = o1 + bout[1];
        }
    }
}

extern "C" void kernel_launch(void* const* d_in, const int* in_sizes, int n_in,
                              void* d_out, int out_size, void* d_ws, size_t ws_size,
                              hipStream_t stream) {
    const float* x     = (const float*)d_in[0];
    const int*   ei    = (const int*)d_in[1];
    const float* Wl1   = (const float*)d_in[2];
    const float* bl1   = (const float*)d_in[3];
    const float* Wr1   = (const float*)d_in[4];
    const float* br1   = (const float*)d_in[5];
    const float* att1  = (const float*)d_in[6];
    const float* bias1 = (const float*)d_in[7];
    const float* Wl2   = (const float*)d_in[8];
    const float* bl2   = (const float*)d_in[9];
    const float* Wr2   = (const float*)d_in[10];
    const float* br2   = (const float*)d_in[11];
    const float* att2  = (const float*)d_in[12];
    const float* bias2 = (const float*)d_in[13];
    const float* Wout  = (const float*)d_in[14];
    const float* bout  = (const float*)d_in[15];

    const int* src = ei;
    const int* dst = ei + EE;

    // ---------- workspace layout ----------
    ushort* hb    = (ushort*)d_ws;                     // [N][512] fp16 (xl|xr)
    ushort* h1_h  = hb + (size_t)NN * 512;             // [N][256] fp16
    ushort* xh    = h1_h + (size_t)NN * 256;           // [N][128] fp16
    ushort* Wst1  = xh + (size_t)NN * DIN;             // [512][128]
    ushort* Wst2  = Wst1 + W1SZ;                       // [512][256]
    int* deg    = (int*)(Wst2 + W2SZ);
    int* inc    = deg + NN;
    int* rowptr = inc + NN;                            // NN+1
    int* wptr   = rowptr + NN + 1;
    int* ssrc   = wptr + NN;                           // E
    int* bsum   = ssrc + EE;                           // 256
    int* boff   = bsum + 256;

    const int scanBlocks = (NN + 255) / 256;
    const int edgeBlocks = (EE + 255) / 256;
    const int nodeBlocks = (NN + 3) / 4;
    const int prepBlocks = (EE + NX8 + W1SZ + W2SZ + 255) / 256;
    dim3 gemmGrid((NN + 127) / 128, 4);

    // ---------- CSR build + converts ----------
    hipMemsetAsync(deg, 0, NN * sizeof(int), stream);
    prep<<<prepBlocks, 256, 0, stream>>>(dst, deg, x, xh, Wl1, Wr1, Wl2, Wr2, Wst1, Wst2);
    scanA<<<scanBlocks, 256, 0, stream>>>(deg, inc, bsum);
    scanB<<<1, 256, 0, stream>>>(bsum, boff, scanBlocks);
    scanC<<<scanBlocks + 1, 256, 0, stream>>>(deg, inc, boff, rowptr, wptr);
    scatter_src<<<edgeBlocks, 256, 0, stream>>>(src, dst, wptr, ssrc);

    // ---------- layer 1 ----------
    gemm_mfma2<<<gemmGrid, 256, 0, stream>>>(xh, Wst1, bl1, br1, hb, NN, DIN);
    gat_node<1><<<nodeBlocks, 256, 0, stream>>>(hb, att1, rowptr, ssrc,
                                                bias1, nullptr, nullptr, h1_h, nullptr);

    // ---------- layer 2 ----------
    gemm_mfma2<<<gemmGrid, 256, 0, stream>>>(h1_h, Wst2, bl2, br2, hb, NN, 256);
    gat_node<2><<<nodeBlocks, 256, 0, stream>>>(hb, att2, rowptr, ssrc,
                                                bias2, Wout, bout, nullptr, (float*)d_out);
}

// Round 15
// 293.385 us; speedup vs baseline: 1.0315x; 1.0140x over previous
//
#include <hip/hip_runtime.h>
#include <math.h>

#define NN 50000
#define EE 800000
#define DIN 128
#define F1 256          // HEADS*HID
#define NEG_SLOPE 0.2f

typedef _Float16 half8 __attribute__((ext_vector_type(8)));
typedef _Float16 h2 __attribute__((ext_vector_type(2)));
typedef float f32x4 __attribute__((ext_vector_type(4)));

#if __has_builtin(__builtin_amdgcn_fdot2)
#define FDOT2(a, b, c) __builtin_amdgcn_fdot2((a), (b), (c), false)
#else
#define FDOT2(a, b, c) ((float)(a)[0] * (float)(b)[0] + ((float)(a)[1] * (float)(b)[1] + (c)))
#endif

__device__ __forceinline__ ushort f2h(float f) {
    _Float16 h = (_Float16)f;
    return __builtin_bit_cast(ushort, h);
}

__device__ __forceinline__ void gload16(const void* g, void* l) {
    __builtin_amdgcn_global_load_lds(
        (const __attribute__((address_space(1))) void*)g,
        (__attribute__((address_space(3))) void*)l, 16, 0, 0);
}

// DPP-based xor-add reduce within aligned 8-lane groups (VALU pipe).
#if __has_builtin(__builtin_amdgcn_mov_dpp)
#define DPPADD(x, ctrl) ((x) + __int_as_float(__builtin_amdgcn_mov_dpp(__float_as_int(x), (ctrl), 0xF, 0xF, true)))
#define RED8(x) do { x = DPPADD(x, 0xB1); x = DPPADD(x, 0x4E); x = DPPADD(x, 0x141); } while (0)
#else
#define RED8(x) do { x += __shfl_xor(x, 1, 64); x += __shfl_xor(x, 2, 64); x += __shfl_xor(x, 4, 64); } while (0)
#endif

// ================= prep: count degrees + convert x and weights to fp16 =================
#define NX8 (NN * DIN / 8)      // 800000
#define W1SZ (512 * DIN)        // 65536
#define W2SZ (512 * 256)        // 131072
__global__ __launch_bounds__(256) void prep(
        const int* __restrict__ dst, int* __restrict__ deg,
        const float* __restrict__ x, ushort* __restrict__ xh,
        const float* __restrict__ Wl1, const float* __restrict__ Wr1,
        const float* __restrict__ Wl2, const float* __restrict__ Wr2,
        ushort* __restrict__ Wst1, ushort* __restrict__ Wst2) {
    int idx = blockIdx.x * 256 + threadIdx.x;
    if (idx < EE) {
        atomicAdd(&deg[dst[idx]], 1);
    } else if (idx < EE + NX8) {
        int i = idx - EE;
        float4 v0 = *(const float4*)(x + (size_t)i * 8);
        float4 v1 = *(const float4*)(x + (size_t)i * 8 + 4);
        ushort4 o0, o1;
        o0.x = f2h(v0.x); o0.y = f2h(v0.y); o0.z = f2h(v0.z); o0.w = f2h(v0.w);
        o1.x = f2h(v1.x); o1.y = f2h(v1.y); o1.z = f2h(v1.z); o1.w = f2h(v1.w);
        *(ushort4*)(xh + (size_t)i * 8) = o0;
        *(ushort4*)(xh + (size_t)i * 8 + 4) = o1;
    } else {
        int j = idx - EE - NX8;
        if (j < W1SZ) {
            int n = j >> 7, k = j & 127;        // Wst1[n][k], K=128
            float v = (n < 256) ? Wl1[(size_t)k * 256 + n] : Wr1[(size_t)k * 256 + (n - 256)];
            Wst1[j] = f2h(v);
        } else if (j < W1SZ + W2SZ) {
            int jj = j - W1SZ;
            int n = jj >> 8, k = jj & 255;      // Wst2[n][k], K=256
            float v = (n < 256) ? Wl2[(size_t)k * 256 + n] : Wr2[(size_t)k * 256 + (n - 256)];
            Wst2[jj] = f2h(v);
        }
    }
}

// ================= fused fp16 MFMA GEMM: C[M,512] = A[M,K] @ [Wl;Wr]^T + bias =================
__global__ __launch_bounds__(256) void gemm_mfma2(
        const ushort* __restrict__ Ah, const ushort* __restrict__ Wst,
        const float* __restrict__ biasL, const float* __restrict__ biasR,
        ushort* __restrict__ Ch, int M, int K) {
    __shared__ ushort As[128 * 32];   // [row][slot*8]  (slot-rotated)
    __shared__ ushort Ws[128 * 32];   // [col][slot*8]
    const int tid = threadIdx.x;
    const int wave = tid >> 6, lane = tid & 63;
    const int row0 = blockIdx.x * 128;
    const int col0 = blockIdx.y * 128;          // 0..3 -> 512 cols
    const int wr = wave >> 1, wc = wave & 1;
    const int g = lane >> 4, lr = lane & 15;

    f32x4 acc[4][4];
    #pragma unroll
    for (int m = 0; m < 4; m++)
        #pragma unroll
        for (int n = 0; n < 4; n++) acc[m][n] = (f32x4){0.f, 0.f, 0.f, 0.f};

    for (int k0 = 0; k0 < K; k0 += 32) {
        #pragma unroll
        for (int j = 0; j < 2; j++) {
            int cc = j * 256 + wave * 64 + lane;       // 0..511, 8 ushorts each
            int rr = cc >> 2;
            int kp = ((cc & 3) - (rr >> 1)) & 3;       // slot rotation (stage side)
            int gr = row0 + rr; if (gr >= M) gr = M - 1;
            gload16(Ah + (size_t)gr * K + k0 + kp * 8, &As[(j * 256 + wave * 64) * 8]);
            gload16(Wst + (size_t)(col0 + rr) * K + k0 + kp * 8, &Ws[(j * 256 + wave * 64) * 8]);
        }
        __syncthreads();
        half8 af[4], bfr[4];
        #pragma unroll
        for (int m = 0; m < 4; m++) {
            int row = wr * 64 + m * 16 + lr;
            int slot = (g + (row >> 1)) & 3;           // rotation (read side)
            af[m] = *(const half8*)&As[(row * 4 + slot) * 8];
        }
        #pragma unroll
        for (int n = 0; n < 4; n++) {
            int col = wc * 64 + n * 16 + lr;
            int slot = (g + (col >> 1)) & 3;
            bfr[n] = *(const half8*)&Ws[(col * 4 + slot) * 8];
        }
        #pragma unroll
        for (int m = 0; m < 4; m++)
            #pragma unroll
            for (int n = 0; n < 4; n++)
                acc[m][n] = __builtin_amdgcn_mfma_f32_16x16x32_f16(af[m], bfr[n], acc[m][n], 0, 0, 0);
        __syncthreads();
    }
    #pragma unroll
    for (int m = 0; m < 4; m++) {
        int rowb = row0 + wr * 64 + m * 16 + g * 4;
        #pragma unroll
        for (int n = 0; n < 4; n++) {
            int col = col0 + wc * 64 + n * 16 + lr;
            float b = (col < 256) ? biasL[col] : biasR[col - 256];
            #pragma unroll
            for (int j = 0; j < 4; j++) {
                int grow = rowb + j;
                if (grow < M) Ch[(size_t)grow * 512 + col] = f2h(acc[m][n][j] + b);
            }
        }
    }
}

// ================= CSR scan kernels =================
__global__ __launch_bounds__(256) void scanA(
        const int* __restrict__ deg, int* __restrict__ inc, int* __restrict__ bsum) {
    __shared__ int s[256];
    int i = blockIdx.x * 256 + threadIdx.x;
    int v = (i < NN) ? deg[i] : 0;
    s[threadIdx.x] = v;
    __syncthreads();
    #pragma unroll
    for (int off = 1; off < 256; off <<= 1) {
        int t = (threadIdx.x >= off) ? s[threadIdx.x - off] : 0;
        __syncthreads();
        s[threadIdx.x] += t;
        __syncthreads();
    }
    if (i < NN) inc[i] = s[threadIdx.x];
    if (threadIdx.x == 255) bsum[blockIdx.x] = s[255];
}

__global__ __launch_bounds__(256) void scanB(
        const int* __restrict__ bsum, int* __restrict__ boff, int nblocks) {
    __shared__ int s[256];
    int v = (threadIdx.x < nblocks) ? bsum[threadIdx.x] : 0;
    s[threadIdx.x] = v;
    __syncthreads();
    #pragma unroll
    for (int off = 1; off < 256; off <<= 1) {
        int t = (threadIdx.x >= off) ? s[threadIdx.x - off] : 0;
        __syncthreads();
        s[threadIdx.x] += t;
        __syncthreads();
    }
    if (threadIdx.x < nblocks) boff[threadIdx.x] = s[threadIdx.x] - v;
}

__global__ __launch_bounds__(256) void scanC(
        const int* __restrict__ deg, const int* __restrict__ inc,
        const int* __restrict__ boff,
        int* __restrict__ rowptr, int* __restrict__ wptr) {
    int i = blockIdx.x * 256 + threadIdx.x;
    if (i < NN) {
        int ex = inc[i] - deg[i] + boff[i >> 8];
        rowptr[i] = ex;
        wptr[i] = ex;
    } else if (i == NN) {
        rowptr[NN] = EE;
    }
}

__global__ __launch_bounds__(256) void scatter_src(
        const int* __restrict__ src, const int* __restrict__ dst,
        int* __restrict__ wptr, int* __restrict__ ssrc) {
    int e = blockIdx.x * 256 + threadIdx.x;
    if (e < EE) {
        int pos = atomicAdd(&wptr[dst[e]], 1);
        ssrc[pos] = src[e];
    }
}

// ================= fused GATv2 node kernel =================
// fp16 packed, 2 edges/iteration, DECOUPLED 3-stage pipeline:
// indices run two iterations ahead of math, rows one iteration ahead.
// Within an iteration, the index load (it+4) and row gather (it+2, using
// indices fetched last iteration) are both independent of this iteration's
// math -- no serial index->gather chain in the steady-state window.
template<int MODE>
__global__ __launch_bounds__(256) void gat_node(
        const ushort* __restrict__ hb,
        const float* __restrict__ att,
        const int* __restrict__ rowptr, const int* __restrict__ ssrc,
        const float* __restrict__ bias,
        const float* __restrict__ Wout, const float* __restrict__ bout,
        ushort* __restrict__ out_h, float* __restrict__ out_f) {
    int node = blockIdx.x * 4 + (threadIdx.x >> 6);
    int lane = threadIdx.x & 63;
    if (node >= NN) return;
    const int half = lane >> 5;
    const int hl = lane & 31;

    const int beg = rowptr[node];
    const int cnt = rowptr[node + 1] - beg;
    const int cntA = (cnt + 1) >> 1;
    const int mybeg = beg + half * cntA;
    const int mycnt = half ? (cnt - cntA) : cntA;

    const h2 nsh = { (_Float16)NEG_SLOPE, (_Float16)NEG_SLOPE };

    // xr (fp16 packed) and att (converted to fp16 pairs)
    h2 rrh[4], ath[4];
    {
        uint4 ur = *(const uint4*)(hb + (size_t)node * 512 + 256 + hl * 8);
        rrh[0] = __builtin_bit_cast(h2, ur.x);
        rrh[1] = __builtin_bit_cast(h2, ur.y);
        rrh[2] = __builtin_bit_cast(h2, ur.z);
        rrh[3] = __builtin_bit_cast(h2, ur.w);
        const float* pat = att + hl * 8;
        #pragma unroll
        for (int k2 = 0; k2 < 4; k2++) {
            h2 t; t[0] = (_Float16)pat[k2 * 2]; t[1] = (_Float16)pat[k2 * 2 + 1];
            ath[k2] = t;
        }
    }

    float den = 0.f;
    float acc[8] = {0.f, 0.f, 0.f, 0.f, 0.f, 0.f, 0.f, 0.f};

    const int safe = (cnt > 0) ? beg : 0;    // ssrc[0] always valid; result unused

    // ---- pipeline prologue ----
    // rows for it=0:
    int i0 = (0 < mycnt) ? mybeg + 0 : safe;
    int i1 = (1 < mycnt) ? mybeg + 1 : safe;
    int cs0 = ssrc[i0];
    int cs1 = ssrc[i1];
    uint4 cur0 = *(const uint4*)(hb + (size_t)cs0 * 512 + hl * 8);
    uint4 cur1 = *(const uint4*)(hb + (size_t)cs1 * 512 + hl * 8);
    // indices for it=2:
    int j0 = (2 < mycnt) ? mybeg + 2 : safe;
    int j1 = (3 < mycnt) ? mybeg + 3 : safe;
    int ns0 = ssrc[j0];
    int ns1 = ssrc[j1];

    for (int it = 0; it < cntA; it += 2) {
        const bool v0 = (it < mycnt);
        const bool v1 = (it + 1 < mycnt);

        // ---- issue index loads for it+4 (independent) ----
        int f0 = (it + 4 < mycnt) ? mybeg + it + 4 : safe;
        int f1 = (it + 5 < mycnt) ? mybeg + it + 5 : safe;
        int fs0 = ssrc[f0];
        int fs1 = ssrc[f1];

        // ---- issue row gathers for it+2 using last iteration's indices ----
        uint4 nxt0 = *(const uint4*)(hb + (size_t)ns0 * 512 + hl * 8);
        uint4 nxt1 = *(const uint4*)(hb + (size_t)ns1 * 512 + hl * 8);

        // ---- math on current stage ----
        h2 xa[4], xb[4];
        xa[0] = __builtin_bit_cast(h2, cur0.x); xb[0] = __builtin_bit_cast(h2, cur1.x);
        xa[1] = __builtin_bit_cast(h2, cur0.y); xb[1] = __builtin_bit_cast(h2, cur1.y);
        xa[2] = __builtin_bit_cast(h2, cur0.z); xb[2] = __builtin_bit_cast(h2, cur1.z);
        xa[3] = __builtin_bit_cast(h2, cur0.w); xb[3] = __builtin_bit_cast(h2, cur1.w);

        float pa = 0.f, pb = 0.f;
        #pragma unroll
        for (int k2 = 0; k2 < 4; k2++) {
            h2 va = xa[k2] + rrh[k2];
            h2 vb = xb[k2] + rrh[k2];
            h2 la = __builtin_elementwise_max(va, va * nsh);
            h2 lb = __builtin_elementwise_max(vb, vb * nsh);
            pa = FDOT2(la, ath[k2], pa);
            pb = FDOT2(lb, ath[k2], pb);
        }
        RED8(pa);
        RED8(pb);

        float p0f = v0 ? __expf(pa) : 0.f;
        float p1f = v1 ? __expf(pb) : 0.f;
        den += p0f + p1f;
        #pragma unroll
        for (int k2 = 0; k2 < 4; k2++) {
            acc[k2 * 2 + 0] = fmaf(p0f, (float)xa[k2][0], acc[k2 * 2 + 0]);
            acc[k2 * 2 + 1] = fmaf(p0f, (float)xa[k2][1], acc[k2 * 2 + 1]);
            acc[k2 * 2 + 0] = fmaf(p1f, (float)xb[k2][0], acc[k2 * 2 + 0]);
            acc[k2 * 2 + 1] = fmaf(p1f, (float)xb[k2][1], acc[k2 * 2 + 1]);
        }

        // ---- rotate pipeline ----
        cur0 = nxt0; cur1 = nxt1;
        ns0 = fs0;   ns1 = fs1;
    }

    // merge the two half-wave streams
    den += __shfl_xor(den, 32, 64);
    float inv = den > 0.f ? 1.0f / den : 0.f;
    float o[8];
    #pragma unroll
    for (int c = 0; c < 8; c++) {
        float t = acc[c] + __shfl_xor(acc[c], 32, 64);
        o[c] = t * inv;
    }

    if (MODE == 1) {
        // bias + relu -> fp16, packed [N][256]; half 0 writes 16B
        uint4 ow;
        float t0, t1;
        t0 = o[0] + bias[hl * 8 + 0]; t0 = t0 > 0.f ? t0 : 0.f;
        t1 = o[1] + bias[hl * 8 + 1]; t1 = t1 > 0.f ? t1 : 0.f;
        ow.x = (unsigned)f2h(t0) | ((unsigned)f2h(t1) << 16);
        t0 = o[2] + bias[hl * 8 + 2]; t0 = t0 > 0.f ? t0 : 0.f;
        t1 = o[3] + bias[hl * 8 + 3]; t1 = t1 > 0.f ? t1 : 0.f;
        ow.y = (unsigned)f2h(t0) | ((unsigned)f2h(t1) << 16);
        t0 = o[4] + bias[hl * 8 + 4]; t0 = t0 > 0.f ? t0 : 0.f;
        t1 = o[5] + bias[hl * 8 + 5]; t1 = t1 > 0.f ? t1 : 0.f;
        ow.z = (unsigned)f2h(t0) | ((unsigned)f2h(t1) << 16);
        t0 = o[6] + bias[hl * 8 + 6]; t0 = t0 > 0.f ? t0 : 0.f;
        t1 = o[7] + bias[hl * 8 + 7]; t1 = t1 > 0.f ? t1 : 0.f;
        ow.w = (unsigned)f2h(t0) | ((unsigned)f2h(t1) << 16);
        if (half == 0)
            *(uint4*)(out_h + (size_t)node * 256 + hl * 8) = ow;
    } else {
        // head-mean (lanes hl^8, hl^16) + bias2, then @ Wout + bout
        #pragma unroll
        for (int c = 0; c < 8; c++) {
            o[c] += __shfl_xor(o[c], 8, 64);
            o[c] += __shfl_xor(o[c], 16, 64);
        }
        int c64 = (hl & 7) * 8;
        float o0 = 0.f, o1 = 0.f;
        #pragma unroll
        for (int c = 0; c < 8; c++) {
            float t = 0.25f * o[c] + bias[c64 + c];
            o0 = fmaf(t, Wout[(c64 + c) * 2 + 0], o0);
            o1 = fmaf(t, Wout[(c64 + c) * 2 + 1], o1);
        }
        o0 += __shfl_xor(o0, 1, 64); o1 += __shfl_xor(o1, 1, 64);
        o0 += __shfl_xor(o0, 2, 64); o1 += __shfl_xor(o1, 2, 64);
        o0 += __shfl_xor(o0, 4, 64); o1 += __shfl_xor(o1, 4, 64);
        if (lane == 0) {
            out_f[(size_t)node * 2 + 0] = o0 + bout[0];
            out_f[(size_t)node * 2 + 1] = o1 + bout[1];
        }
    }
}

extern "C" void kernel_launch(void* const* d_in, const int* in_sizes, int n_in,
                              void* d_out, int out_size, void* d_ws, size_t ws_size,
                              hipStream_t stream) {
    const float* x     = (const float*)d_in[0];
    const int*   ei    = (const int*)d_in[1];
    const float* Wl1   = (const float*)d_in[2];
    const float* bl1   = (const float*)d_in[3];
    const float* Wr1   = (const float*)d_in[4];
    const float* br1   = (const float*)d_in[5];
    const float* att1  = (const float*)d_in[6];
    const float* bias1 = (const float*)d_in[7];
    const float* Wl2   = (const float*)d_in[8];
    const float* bl2   = (const float*)d_in[9];
    const float* Wr2   = (const float*)d_in[10];
    const float* br2   = (const float*)d_in[11];
    const float* att2  = (const float*)d_in[12];
    const float* bias2 = (const float*)d_in[13];
    const float* Wout  = (const float*)d_in[14];
    const float* bout  = (const float*)d_in[15];

    const int* src = ei;
    const int* dst = ei + EE;

    // ---------- workspace layout ----------
    ushort* hb    = (ushort*)d_ws;                     // [N][512] fp16 (xl|xr)
    ushort* h1_h  = hb + (size_t)NN * 512;             // [N][256] fp16
    ushort* xh    = h1_h + (size_t)NN * 256;           // [N][128] fp16
    ushort* Wst1  = xh + (size_t)NN * DIN;             // [512][128]
    ushort* Wst2  = Wst1 + W1SZ;                       // [512][256]
    int* deg    = (int*)(Wst2 + W2SZ);
    int* inc    = deg + NN;
    int* rowptr = inc + NN;                            // NN+1
    int* wptr   = rowptr + NN + 1;
    int* ssrc   = wptr + NN;                           // E
    int* bsum   = ssrc + EE;                           // 256
    int* boff   = bsum + 256;

    const int scanBlocks = (NN + 255) / 256;
    const int edgeBlocks = (EE + 255) / 256;
    const int nodeBlocks = (NN + 3) / 4;
    const int prepBlocks = (EE + NX8 + W1SZ + W2SZ + 255) / 256;
    dim3 gemmGrid((NN + 127) / 128, 4);

    // ---------- CSR build + converts ----------
    hipMemsetAsync(deg, 0, NN * sizeof(int), stream);
    prep<<<prepBlocks, 256, 0, stream>>>(dst, deg, x, xh, Wl1, Wr1, Wl2, Wr2, Wst1, Wst2);
    scanA<<<scanBlocks, 256, 0, stream>>>(deg, inc, bsum);
    scanB<<<1, 256, 0, stream>>>(bsum, boff, scanBlocks);
    scanC<<<scanBlocks + 1, 256, 0, stream>>>(deg, inc, boff, rowptr, wptr);
    scatter_src<<<edgeBlocks, 256, 0, stream>>>(src, dst, wptr, ssrc);

    // ---------- layer 1 ----------
    gemm_mfma2<<<gemmGrid, 256, 0, stream>>>(xh, Wst1, bl1, br1, hb, NN, DIN);
    gat_node<1><<<nodeBlocks, 256, 0, stream>>>(hb, att1, rowptr, ssrc,
                                                bias1, nullptr, nullptr, h1_h, nullptr);

    // ---------- layer 2 ----------
    gemm_mfma2<<<gemmGrid, 256, 0, stream>>>(h1_h, Wst2, bl2, br2, hb, NN, 256);
    gat_node<2><<<nodeBlocks, 256, 0, stream>>>(hb, att2, rowptr, ssrc,
                                                bias2, Wout, bout, nullptr, (float*)d_out);
}